// Round 1
// baseline (453.055 us; speedup 1.0000x reference)
//
#include <hip/hip_runtime.h>
#include <math.h>

#define Bb   2
#define Rr   384
#define CMd  384
#define CZ   128
#define Hh   12
#define DHd  32

#define WL           1.7320508075688772f   // sqrt(3)
#define WC           4.242640687119285f    // sqrt(18) = (2/(9*4))^-0.5
#define INV_SQRT_DH  0.17677669529663687f  // 32^-0.5

#define SZ_R   (Bb*Hh*Rr*DHd)      // 294912
#define SZ_T   (Bb*Hh*Rr*12)      // 110592
#define SZ_S   (Bb*Hh*Rr)         // 9216
#define SZ_A   ((long)Bb*Hh*Rr*Rr) // 3538944
#define SZ_O   (Bb*Rr*Hh*DHd)     // 294912

// ---------------------------------------------------------------- K1: projections
#define K1_ROWS 4
__global__ __launch_bounds__(256) void k_proj(
    const float* __restrict__ sing, const float* __restrict__ Wqkv,
    const float* __restrict__ Wqk, const float* __restrict__ bbr,
    const float* __restrict__ bbt,
    float* __restrict__ rq, float* __restrict__ rk, float* __restrict__ rv,
    float* __restrict__ TqF, float* __restrict__ TkF,
    float* __restrict__ Qsq, float* __restrict__ Ksq)
{
  const int t = threadIdx.x;
  const int base = blockIdx.x * K1_ROWS;   // over B*R = 768 rows
  __shared__ float s_l[K1_ROWS][384];
  __shared__ float g_l[K1_ROWS][288];
  __shared__ float rot_l[K1_ROWS][9];
  __shared__ float tr_l[K1_ROWS][3];
  __shared__ float psq[K1_ROWS][96];

  for (int idx = t; idx < K1_ROWS*384; idx += 256)
    s_l[idx/384][idx%384] = sing[(long)base*384 + idx];
  if (t < K1_ROWS*9) rot_l[t/9][t%9] = bbr[(long)base*9 + t];
  if (t < K1_ROWS*3) tr_l[t/3][t%3] = bbt[(long)base*3 + t];
  __syncthreads();

  // qkv = sing @ W_qkv; col = d*36 + which*12 + h
  for (int col = t; col < 1152; col += 256) {
    float acc[K1_ROWS] = {0.f,0.f,0.f,0.f};
    for (int k = 0; k < 384; ++k) {
      float w = Wqkv[(long)k*1152 + col];
      #pragma unroll
      for (int r2 = 0; r2 < K1_ROWS; ++r2) acc[r2] += s_l[r2][k] * w;
    }
    int d = col/36, rem = col - d*36, which = rem/12, h = rem - which*12;
    float* dst = (which == 0) ? rq : (which == 1) ? rk : rv;
    #pragma unroll
    for (int r2 = 0; r2 < K1_ROWS; ++r2) {
      int br = base + r2, b = br / Rr, r = br - b*Rr;
      dst[(((long)b*Hh + h)*Rr + r)*DHd + d] = acc[r2];
    }
  }
  // qk = sing @ W_qk; col = h*24 + s2*12 + p*3 + a
  for (int col = t; col < 288; col += 256) {
    float acc[K1_ROWS] = {0.f,0.f,0.f,0.f};
    for (int k = 0; k < 384; ++k) {
      float w = Wqk[(long)k*288 + col];
      #pragma unroll
      for (int r2 = 0; r2 < K1_ROWS; ++r2) acc[r2] += s_l[r2][k] * w;
    }
    #pragma unroll
    for (int r2 = 0; r2 < K1_ROWS; ++r2) g_l[r2][col] = acc[r2];
  }
  __syncthreads();
  // frame transform: T = g . bbr + bbt ; accumulate per-point |T|^2
  for (int task = t; task < K1_ROWS*96; task += 256) {
    int r2 = task / 96, q = task - r2*96;
    int h = q / 8, rm = q - h*8, s2 = rm / 4, p = rm - s2*4;
    const float* gp = &g_l[r2][h*24 + s2*12 + p*3];
    const float* rot = rot_l[r2];
    int br = base + r2, b = br / Rr, r = br - b*Rr;
    float* dstT = s2 ? TkF : TqF;
    float ss = 0.f;
    #pragma unroll
    for (int k2 = 0; k2 < 3; ++k2) {
      float v = gp[0]*rot[k2] + gp[1]*rot[3+k2] + gp[2]*rot[6+k2] + tr_l[r2][k2];
      dstT[(((long)b*Hh + h)*Rr + r)*12 + p*3 + k2] = v;
      ss += v*v;
    }
    psq[r2][q] = ss;
  }
  __syncthreads();
  for (int task = t; task < K1_ROWS*24; task += 256) {
    int r2 = task / 24, q = task - r2*24;
    int h = q / 2, s2 = q & 1;
    const float* pp = &psq[r2][h*8 + s2*4];
    float sum = pp[0]+pp[1]+pp[2]+pp[3];
    int br = base + r2, b = br / Rr, r = br - b*Rr;
    (s2 ? Ksq : Qsq)[((long)b*Hh + h)*Rr + r] = sum;
  }
}

// ---------------------------------------------------------------- K2: pair bias
__global__ __launch_bounds__(256) void k_pbias(
    const float* __restrict__ pair, const float* __restrict__ Wfc1,
    const float* __restrict__ bfc1, float* __restrict__ pb)
{
  const int t = threadIdx.x;
  const long base = (long)blockIdx.x * 64;   // 64 (b,i,j) rows per block
  __shared__ float tile[64][129];            // +1 pad: conflict-free
  __shared__ float w_l[128][12];
  __shared__ float bias_l[12];
  for (int idx = t; idx < 128*12; idx += 256) w_l[idx/12][idx%12] = Wfc1[idx];
  if (t < 12) bias_l[t] = bfc1[t];
  const float4* src = (const float4*)(pair + base*CZ);
  for (int idx = t; idx < 64*32; idx += 256) {
    float4 v = src[idx];
    int row = idx >> 5, c4 = (idx & 31) << 2;
    tile[row][c4] = v.x; tile[row][c4+1] = v.y; tile[row][c4+2] = v.z; tile[row][c4+3] = v.w;
  }
  __syncthreads();
  int row = t & 63;
  long n = base + row;
  int b = (int)(n / ((long)Rr*Rr));
  long rr2 = n - (long)b*Rr*Rr;
  int i = (int)(rr2 / Rr), j = (int)(rr2 - (long)i*Rr);
  int h0 = t >> 6;                           // h = h0, h0+4, h0+8
  float a0 = bias_l[h0], a1 = bias_l[h0+4], a2 = bias_l[h0+8];
  for (int c = 0; c < 128; ++c) {
    float v = tile[row][c];
    a0 += v*w_l[c][h0]; a1 += v*w_l[c][h0+4]; a2 += v*w_l[c][h0+8];
  }
  long o = (((long)b*Hh + h0)*Rr + i)*Rr + j;
  const long hstride = (long)Rr*Rr*4;
  pb[o] = a0; pb[o + hstride] = a1; pb[o + 2*hstride] = a2;
}

// ---------------------------------------------------------------- K3: scores + softmax
#define ITILE 8
__global__ __launch_bounds__(256) void k_scores(
    const float* __restrict__ rq, const float* __restrict__ rk,
    const float* __restrict__ TqF, const float* __restrict__ TkF,
    const float* __restrict__ Qsq, const float* __restrict__ Ksq,
    const float* __restrict__ gamma, float* __restrict__ attn)
{
  const int t = threadIdx.x;
  const int nt = Rr / ITILE;                 // 48
  const int bh = blockIdx.x / nt;
  const int i0 = (blockIdx.x - bh*nt) * ITILE;
  __shared__ float rk_l[384][33];            // 50.7 KB, conflict-free
  __shared__ float rq_l[32];
  __shared__ float tq_l[12];
  __shared__ float scal[1];
  __shared__ float redm[4], reds[4];

  for (int idx = t; idx < 384*32; idx += 256)
    rk_l[idx >> 5][idx & 31] = rk[(long)bh*Rr*DHd + idx];

  const float g0 = gamma[0];
  const float head_w = log1pf(__expf(g0)) * (WC * 0.5f);

  for (int ii = 0; ii < ITILE; ++ii) {
    const int i = i0 + ii;
    if (t < 32) rq_l[t] = rq[((long)bh*Rr + i)*DHd + t];
    if (t < 12) tq_l[t] = TqF[((long)bh*Rr + i)*12 + t];
    if (t == 0) scal[0] = Qsq[(long)bh*Rr + i];
    __syncthreads();                         // also covers rk_l staging (first iter)
    const float qs = scal[0];
    const long rowbase = ((long)bh*Rr + i)*Rr;

    auto logit_at = [&](int j) -> float {
      float dt = 0.f;
      #pragma unroll
      for (int dd = 0; dd < 32; ++dd) dt += rq_l[dd] * rk_l[j][dd];
      const float4* tk = (const float4*)(TkF + ((long)bh*Rr + j)*12);
      float4 ta = tk[0], tb = tk[1], tc = tk[2];
      float pt = tq_l[0]*ta.x + tq_l[1]*ta.y + tq_l[2]*ta.z + tq_l[3]*ta.w
               + tq_l[4]*tb.x + tq_l[5]*tb.y + tq_l[6]*tb.z + tq_l[7]*tb.w
               + tq_l[8]*tc.x + tq_l[9]*tc.y + tq_l[10]*tc.z + tq_l[11]*tc.w;
      float sqv = qs + Ksq[(long)bh*Rr + j] - 2.f*pt;
      return WL * (attn[rowbase + j] + dt*INV_SQRT_DH + head_w*sqv);
    };

    float l0 = logit_at(t);
    float l1 = (t < 128) ? logit_at(t + 256) : -3.4e38f;
    float m = fmaxf(l0, l1);
    #pragma unroll
    for (int s = 32; s; s >>= 1) m = fmaxf(m, __shfl_xor(m, s, 64));
    if ((t & 63) == 0) redm[t >> 6] = m;
    __syncthreads();
    m = fmaxf(fmaxf(redm[0], redm[1]), fmaxf(redm[2], redm[3]));
    float e0 = __expf(l0 - m);
    float e1 = (t < 128) ? __expf(l1 - m) : 0.f;
    float s = e0 + e1;
    #pragma unroll
    for (int sh = 32; sh; sh >>= 1) s += __shfl_xor(s, sh, 64);
    if ((t & 63) == 0) reds[t >> 6] = s;
    __syncthreads();
    float inv = 1.f / (reds[0] + reds[1] + reds[2] + reds[3]);
    attn[rowbase + t] = e0 * inv;
    if (t < 128) attn[rowbase + t + 256] = e1 * inv;
    __syncthreads();
  }
}

// ---------------------------------------------------------------- K4: value aggregation
__global__ __launch_bounds__(256) void k_agg(
    const float* __restrict__ attn, const float* __restrict__ pair,
    const float* __restrict__ rv, float* __restrict__ o_ihd, float* __restrict__ top)
{
  const int t = threadIdx.x;
  const int bi = blockIdx.x;                 // b*R + i
  const int b = bi / Rr;
  const int i = bi - b*Rr;
  __shared__ float a_l[12][384];
  for (int idx = t; idx < 12*384; idx += 256) {
    int h = idx / 384, j = idx - h*384;
    a_l[h][j] = attn[(((long)b*Hh + h)*Rr + i)*Rr + j];
  }
  __syncthreads();
  // Part A: top[b,i,h,c] = sum_j attn[h][j] * pair[b,i,j,c]
  const int c = t & 127, hh = t >> 7;        // hh in {0,1}; h = hh + 2m
  const float* prow = pair + (long)bi * Rr * CZ;
  float acc0=0,acc1=0,acc2=0,acc3=0,acc4=0,acc5=0;
  for (int j = 0; j < 384; ++j) {
    float v = prow[(long)j*CZ + c];
    acc0 += a_l[hh   ][j]*v;
    acc1 += a_l[hh+2 ][j]*v;
    acc2 += a_l[hh+4 ][j]*v;
    acc3 += a_l[hh+6 ][j]*v;
    acc4 += a_l[hh+8 ][j]*v;
    acc5 += a_l[hh+10][j]*v;
  }
  float* tp = top + ((long)bi*Hh)*CZ + c;
  tp[(long)(hh   )*CZ] = acc0;
  tp[(long)(hh+2 )*CZ] = acc1;
  tp[(long)(hh+4 )*CZ] = acc2;
  tp[(long)(hh+6 )*CZ] = acc3;
  tp[(long)(hh+8 )*CZ] = acc4;
  tp[(long)(hh+10)*CZ] = acc5;
  // Part B: o[b,i,h,d] = sum_j attn[h][j] * rv[b,h,j,d]
  for (int o = t; o < 384; o += 256) {
    int h = o >> 5, dd = o & 31;
    const float* rvp = rv + ((long)b*Hh + h)*Rr*DHd + dd;
    float s = 0.f;
    for (int j = 0; j < 384; ++j) s += a_l[h][j] * rvp[(long)j*DHd];
    o_ihd[(long)bi*384 + o] = s;
  }
}

// ---------------------------------------------------------------- K5: output GEMMs
#define FROWS 4
__global__ __launch_bounds__(256) void k_final(
    const float* __restrict__ o_ihd, const float* __restrict__ top,
    const float* __restrict__ W0, const float* __restrict__ W1,
    float* __restrict__ out)
{
  const int t = threadIdx.x;
  const int rb = blockIdx.x * FROWS;         // over B*R = 768 rows
  __shared__ float a0[FROWS][384];
  __shared__ float a1[FROWS][1536];
  for (int idx = t; idx < FROWS*384;  idx += 256) a0[idx/384 ][idx%384 ] = o_ihd[(long)rb*384 + idx];
  for (int idx = t; idx < FROWS*1536; idx += 256) a1[idx/1536][idx%1536] = top[(long)rb*1536 + idx];
  __syncthreads();
  for (int c = t; c < 384; c += 256) {
    float acc0=0, acc1=0, acc2=0, acc3=0;
    for (int k = 0; k < 384; ++k) {
      float w = W0[(long)k*384 + c];
      acc0 += a0[0][k]*w; acc1 += a0[1][k]*w; acc2 += a0[2][k]*w; acc3 += a0[3][k]*w;
    }
    for (int k = 0; k < 1536; ++k) {
      float w = W1[(long)k*384 + c];
      acc0 += a1[0][k]*w; acc1 += a1[1][k]*w; acc2 += a1[2][k]*w; acc3 += a1[3][k]*w;
    }
    out[(long)(rb+0)*384 + c] = acc0;
    out[(long)(rb+1)*384 + c] = acc1;
    out[(long)(rb+2)*384 + c] = acc2;
    out[(long)(rb+3)*384 + c] = acc3;
  }
}

// ---------------------------------------------------------------- launch
extern "C" void kernel_launch(void* const* d_in, const int* in_sizes, int n_in,
                              void* d_out, int out_size, void* d_ws, size_t ws_size,
                              hipStream_t stream)
{
  (void)in_sizes; (void)n_in; (void)out_size; (void)ws_size;
  const float* pair  = (const float*)d_in[0];
  const float* sing  = (const float*)d_in[1];
  const float* bbr   = (const float*)d_in[2];
  const float* bbt   = (const float*)d_in[3];
  const float* Wqkv  = (const float*)d_in[4];
  const float* Wqk   = (const float*)d_in[5];
  const float* Wfc1  = (const float*)d_in[6];
  const float* bfc1  = (const float*)d_in[7];
  const float* W0    = (const float*)d_in[8];
  const float* W1    = (const float*)d_in[9];
  const float* gamma = (const float*)d_in[10];
  float* out = (float*)d_out;

  float* ws    = (float*)d_ws;
  float* rq    = ws;
  float* rk    = rq  + SZ_R;
  float* rv    = rk  + SZ_R;
  float* TqF   = rv  + SZ_R;
  float* TkF   = TqF + SZ_T;
  float* Qsq   = TkF + SZ_T;
  float* Ksq   = Qsq + SZ_S;
  float* attn  = Ksq + SZ_S;
  float* o_ihd = attn + SZ_A;
  float* top   = o_ihd + SZ_O;

  k_proj<<<dim3(Bb*Rr/K1_ROWS), dim3(256), 0, stream>>>(
      sing, Wqkv, Wqk, bbr, bbt, rq, rk, rv, TqF, TkF, Qsq, Ksq);
  k_pbias<<<dim3(Bb*Rr*Rr/64), dim3(256), 0, stream>>>(pair, Wfc1, bfc1, attn);
  k_scores<<<dim3(Bb*Hh*(Rr/ITILE)), dim3(256), 0, stream>>>(
      rq, rk, TqF, TkF, Qsq, Ksq, gamma, attn);
  k_agg<<<dim3(Bb*Rr), dim3(256), 0, stream>>>(attn, pair, rv, o_ihd, top);
  k_final<<<dim3(Bb*Rr/FROWS), dim3(256), 0, stream>>>(o_ihd, top, W0, W1, out);
}

// Round 2
// 374.611 us; speedup vs baseline: 1.2094x; 1.2094x over previous
//
#include <hip/hip_runtime.h>
#include <math.h>

#define Bb   2
#define Rr   384
#define CMd  384
#define CZ   128
#define Hh   12
#define DHd  32

#define WL           1.7320508075688772f   // sqrt(3)
#define WC           4.242640687119285f    // sqrt(18) = (2/(9*4))^-0.5
#define INV_SQRT_DH  0.17677669529663687f  // 32^-0.5

#define SZ_R   (Bb*Hh*Rr*DHd)      // 294912
#define SZ_T   (Bb*Hh*Rr*12)      // 110592
#define SZ_S   (Bb*Hh*Rr)         // 9216
#define SZ_A   ((long)Bb*Hh*Rr*Rr) // 3538944
#define SZ_O   (Bb*Rr*Hh*DHd)     // 294912

// ---------------------------------------------------------------- K1: projections
#define K1_ROWS 4
__global__ __launch_bounds__(256) void k_proj(
    const float* __restrict__ sing, const float* __restrict__ Wqkv,
    const float* __restrict__ Wqk, const float* __restrict__ bbr,
    const float* __restrict__ bbt,
    float* __restrict__ rq, float* __restrict__ rk, float* __restrict__ rv,
    float* __restrict__ TqF, float* __restrict__ TkF,
    float* __restrict__ Qsq, float* __restrict__ Ksq)
{
  const int t = threadIdx.x;
  const int base = blockIdx.x * K1_ROWS;   // over B*R = 768 rows
  __shared__ float s_l[K1_ROWS][384];
  __shared__ float g_l[K1_ROWS][288];
  __shared__ float rot_l[K1_ROWS][9];
  __shared__ float tr_l[K1_ROWS][3];
  __shared__ float psq[K1_ROWS][96];

  for (int idx = t; idx < K1_ROWS*384; idx += 256)
    s_l[idx/384][idx%384] = sing[(long)base*384 + idx];
  if (t < K1_ROWS*9) rot_l[t/9][t%9] = bbr[(long)base*9 + t];
  if (t < K1_ROWS*3) tr_l[t/3][t%3] = bbt[(long)base*3 + t];
  __syncthreads();

  // qkv = sing @ W_qkv; col = d*36 + which*12 + h
  for (int col = t; col < 1152; col += 256) {
    float acc[K1_ROWS] = {0.f,0.f,0.f,0.f};
    for (int k = 0; k < 384; ++k) {
      float w = Wqkv[(long)k*1152 + col];
      #pragma unroll
      for (int r2 = 0; r2 < K1_ROWS; ++r2) acc[r2] += s_l[r2][k] * w;
    }
    int d = col/36, rem = col - d*36, which = rem/12, h = rem - which*12;
    float* dst = (which == 0) ? rq : (which == 1) ? rk : rv;
    #pragma unroll
    for (int r2 = 0; r2 < K1_ROWS; ++r2) {
      int br = base + r2, b = br / Rr, r = br - b*Rr;
      dst[(((long)b*Hh + h)*Rr + r)*DHd + d] = acc[r2];
    }
  }
  // qk = sing @ W_qk; col = h*24 + s2*12 + p*3 + a
  for (int col = t; col < 288; col += 256) {
    float acc[K1_ROWS] = {0.f,0.f,0.f,0.f};
    for (int k = 0; k < 384; ++k) {
      float w = Wqk[(long)k*288 + col];
      #pragma unroll
      for (int r2 = 0; r2 < K1_ROWS; ++r2) acc[r2] += s_l[r2][k] * w;
    }
    #pragma unroll
    for (int r2 = 0; r2 < K1_ROWS; ++r2) g_l[r2][col] = acc[r2];
  }
  __syncthreads();
  // frame transform: T = g . bbr + bbt ; accumulate per-point |T|^2
  for (int task = t; task < K1_ROWS*96; task += 256) {
    int r2 = task / 96, q = task - r2*96;
    int h = q / 8, rm = q - h*8, s2 = rm / 4, p = rm - s2*4;
    const float* gp = &g_l[r2][h*24 + s2*12 + p*3];
    const float* rot = rot_l[r2];
    int br = base + r2, b = br / Rr, r = br - b*Rr;
    float* dstT = s2 ? TkF : TqF;
    float ss = 0.f;
    #pragma unroll
    for (int k2 = 0; k2 < 3; ++k2) {
      float v = gp[0]*rot[k2] + gp[1]*rot[3+k2] + gp[2]*rot[6+k2] + tr_l[r2][k2];
      dstT[(((long)b*Hh + h)*Rr + r)*12 + p*3 + k2] = v;
      ss += v*v;
    }
    psq[r2][q] = ss;
  }
  __syncthreads();
  for (int task = t; task < K1_ROWS*24; task += 256) {
    int r2 = task / 24, q = task - r2*24;
    int h = q / 2, s2 = q & 1;
    const float* pp = &psq[r2][h*8 + s2*4];
    float sum = pp[0]+pp[1]+pp[2]+pp[3];
    int br = base + r2, b = br / Rr, r = br - b*Rr;
    (s2 ? Ksq : Qsq)[((long)b*Hh + h)*Rr + r] = sum;
  }
}

// ---------------------------------------------------------------- K2: pair bias
__global__ __launch_bounds__(256) void k_pbias(
    const float* __restrict__ pair, const float* __restrict__ Wfc1,
    const float* __restrict__ bfc1, float* __restrict__ pb)
{
  const int t = threadIdx.x;
  const long base = (long)blockIdx.x * 64;   // 64 (b,i,j) rows per block
  __shared__ float tile[64][129];            // +1 pad: conflict-free
  __shared__ float w_l[128][12];
  __shared__ float bias_l[12];
  for (int idx = t; idx < 128*12; idx += 256) w_l[idx/12][idx%12] = Wfc1[idx];
  if (t < 12) bias_l[t] = bfc1[t];
  const float4* src = (const float4*)(pair + base*CZ);
  for (int idx = t; idx < 64*32; idx += 256) {
    float4 v = src[idx];
    int row = idx >> 5, c4 = (idx & 31) << 2;
    tile[row][c4] = v.x; tile[row][c4+1] = v.y; tile[row][c4+2] = v.z; tile[row][c4+3] = v.w;
  }
  __syncthreads();
  int row = t & 63;
  long n = base + row;
  int b = (int)(n / ((long)Rr*Rr));
  long rr2 = n - (long)b*Rr*Rr;
  int i = (int)(rr2 / Rr), j = (int)(rr2 - (long)i*Rr);
  int h0 = t >> 6;                           // h = h0, h0+4, h0+8
  float a0 = bias_l[h0], a1 = bias_l[h0+4], a2 = bias_l[h0+8];
  for (int c = 0; c < 128; ++c) {
    float v = tile[row][c];
    a0 += v*w_l[c][h0]; a1 += v*w_l[c][h0+4]; a2 += v*w_l[c][h0+8];
  }
  long o = (((long)b*Hh + h0)*Rr + i)*Rr + j;
  const long hstride = (long)Rr*Rr*4;
  pb[o] = a0; pb[o + hstride] = a1; pb[o + 2*hstride] = a2;
}

// ---------------------------------------------------------------- K3: scores + softmax
#define ITILE 8
__global__ __launch_bounds__(256) void k_scores(
    const float* __restrict__ rq, const float* __restrict__ rk,
    const float* __restrict__ TqF, const float* __restrict__ TkF,
    const float* __restrict__ Qsq, const float* __restrict__ Ksq,
    const float* __restrict__ gamma, float* __restrict__ attn)
{
  const int t = threadIdx.x;
  const int nt = Rr / ITILE;                 // 48
  const int bh = blockIdx.x / nt;
  const int i0 = (blockIdx.x - bh*nt) * ITILE;
  __shared__ float rk_l[384][33];            // 50.7 KB, conflict-free
  __shared__ float rq_l[32];
  __shared__ float tq_l[12];
  __shared__ float scal[1];
  __shared__ float redm[4], reds[4];

  for (int idx = t; idx < 384*32; idx += 256)
    rk_l[idx >> 5][idx & 31] = rk[(long)bh*Rr*DHd + idx];

  const float g0 = gamma[0];
  const float head_w = log1pf(__expf(g0)) * (WC * 0.5f);

  for (int ii = 0; ii < ITILE; ++ii) {
    const int i = i0 + ii;
    if (t < 32) rq_l[t] = rq[((long)bh*Rr + i)*DHd + t];
    if (t < 12) tq_l[t] = TqF[((long)bh*Rr + i)*12 + t];
    if (t == 0) scal[0] = Qsq[(long)bh*Rr + i];
    __syncthreads();                         // also covers rk_l staging (first iter)
    const float qs = scal[0];
    const long rowbase = ((long)bh*Rr + i)*Rr;

    auto logit_at = [&](int j) -> float {
      float dt = 0.f;
      #pragma unroll
      for (int dd = 0; dd < 32; ++dd) dt += rq_l[dd] * rk_l[j][dd];
      const float4* tk = (const float4*)(TkF + ((long)bh*Rr + j)*12);
      float4 ta = tk[0], tb = tk[1], tc = tk[2];
      float pt = tq_l[0]*ta.x + tq_l[1]*ta.y + tq_l[2]*ta.z + tq_l[3]*ta.w
               + tq_l[4]*tb.x + tq_l[5]*tb.y + tq_l[6]*tb.z + tq_l[7]*tb.w
               + tq_l[8]*tc.x + tq_l[9]*tc.y + tq_l[10]*tc.z + tq_l[11]*tc.w;
      float sqv = qs + Ksq[(long)bh*Rr + j] - 2.f*pt;
      return WL * (attn[rowbase + j] + dt*INV_SQRT_DH + head_w*sqv);
    };

    float l0 = logit_at(t);
    float l1 = (t < 128) ? logit_at(t + 256) : -3.4e38f;
    float m = fmaxf(l0, l1);
    #pragma unroll
    for (int s = 32; s; s >>= 1) m = fmaxf(m, __shfl_xor(m, s, 64));
    if ((t & 63) == 0) redm[t >> 6] = m;
    __syncthreads();
    m = fmaxf(fmaxf(redm[0], redm[1]), fmaxf(redm[2], redm[3]));
    float e0 = __expf(l0 - m);
    float e1 = (t < 128) ? __expf(l1 - m) : 0.f;
    float s = e0 + e1;
    #pragma unroll
    for (int sh = 32; sh; sh >>= 1) s += __shfl_xor(s, sh, 64);
    if ((t & 63) == 0) reds[t >> 6] = s;
    __syncthreads();
    float inv = 1.f / (reds[0] + reds[1] + reds[2] + reds[3]);
    attn[rowbase + t] = e0 * inv;
    if (t < 128) attn[rowbase + t + 256] = e1 * inv;
    __syncthreads();
  }
}

// ---------------------------------------------------------------- K4: value aggregation
__global__ __launch_bounds__(256) void k_agg(
    const float* __restrict__ attn, const float* __restrict__ pair,
    const float* __restrict__ rv, float* __restrict__ o_ihd, float* __restrict__ top)
{
  const int t = threadIdx.x;
  const int bi = blockIdx.x;                 // b*R + i
  const int b = bi / Rr;
  const int i = bi - b*Rr;
  __shared__ float a_l[12][384];
  for (int idx = t; idx < 12*384; idx += 256) {
    int h = idx / 384, j = idx - h*384;
    a_l[h][j] = attn[(((long)b*Hh + h)*Rr + i)*Rr + j];
  }
  __syncthreads();
  // Part A: top[b,i,h,c] = sum_j attn[h][j] * pair[b,i,j,c]
  const int c = t & 127, hh = t >> 7;        // hh in {0,1}; h = hh + 2m
  const float* prow = pair + (long)bi * Rr * CZ;
  float acc0=0,acc1=0,acc2=0,acc3=0,acc4=0,acc5=0;
  for (int j = 0; j < 384; ++j) {
    float v = prow[(long)j*CZ + c];
    acc0 += a_l[hh   ][j]*v;
    acc1 += a_l[hh+2 ][j]*v;
    acc2 += a_l[hh+4 ][j]*v;
    acc3 += a_l[hh+6 ][j]*v;
    acc4 += a_l[hh+8 ][j]*v;
    acc5 += a_l[hh+10][j]*v;
  }
  float* tp = top + ((long)bi*Hh)*CZ + c;
  tp[(long)(hh   )*CZ] = acc0;
  tp[(long)(hh+2 )*CZ] = acc1;
  tp[(long)(hh+4 )*CZ] = acc2;
  tp[(long)(hh+6 )*CZ] = acc3;
  tp[(long)(hh+8 )*CZ] = acc4;
  tp[(long)(hh+10)*CZ] = acc5;
  // Part B: o[b,i,h,d] = sum_j attn[h][j] * rv[b,h,j,d]
  for (int o = t; o < 384; o += 256) {
    int h = o >> 5, dd = o & 31;
    const float* rvp = rv + ((long)b*Hh + h)*Rr*DHd + dd;
    float s = 0.f;
    for (int j = 0; j < 384; ++j) s += a_l[h][j] * rvp[(long)j*DHd];
    o_ihd[(long)bi*384 + o] = s;
  }
}

// ---------------------------------------------------------------- K5: output GEMM
// out[768,384] = A[768,1920] @ W[1920,384], A = [o_ihd | top], W = [W0 ; W1]
// BM=8 rows, BN=64 cols per block; grid (96, 6); 2 outputs/thread.
#define K5_BM 8
#define K5_BN 64
#define K5_KC 128
__global__ __launch_bounds__(256) void k_final(
    const float* __restrict__ o_ihd, const float* __restrict__ top,
    const float* __restrict__ W0, const float* __restrict__ W1,
    float* __restrict__ out)
{
  const int t = threadIdx.x;
  const int row0 = blockIdx.x * K5_BM;       // 0..760
  const int col  = blockIdx.y * K5_BN + (t & 63);
  const int rg   = t >> 6;                   // 0..3 -> rows rg*2, rg*2+1
  __shared__ float Al[K5_BM][K5_KC + 4];

  float acc0 = 0.f, acc1 = 0.f;
  const int r0 = rg * 2, r1 = rg * 2 + 1;

  for (int kc = 0; kc < 1920; kc += K5_KC) {
    // stage A chunk: 8 rows x 128 floats; each thread one float4
    {
      int srow = t >> 5;                     // 0..7
      int sc4  = (t & 31) << 2;              // 0..124
      int gk   = kc + sc4;
      const float* src;
      if (gk < 384) src = o_ihd + (long)(row0 + srow)*384 + gk;
      else          src = top   + (long)(row0 + srow)*1536 + (gk - 384);
      float4 v = *(const float4*)src;
      Al[srow][sc4] = v.x; Al[srow][sc4+1] = v.y; Al[srow][sc4+2] = v.z; Al[srow][sc4+3] = v.w;
    }
    __syncthreads();
    const float* wbase;
    long wstride = 384;
    if (kc < 384) wbase = W0 + (long)kc*384 + col;
    else          wbase = W1 + (long)(kc - 384)*384 + col;
    #pragma unroll 8
    for (int k = 0; k < K5_KC; ++k) {
      float w = wbase[(long)k * wstride];
      acc0 += Al[r0][k] * w;
      acc1 += Al[r1][k] * w;
    }
    __syncthreads();
  }
  out[(long)(row0 + r0)*384 + col] = acc0;
  out[(long)(row0 + r1)*384 + col] = acc1;
}

// ---------------------------------------------------------------- launch
extern "C" void kernel_launch(void* const* d_in, const int* in_sizes, int n_in,
                              void* d_out, int out_size, void* d_ws, size_t ws_size,
                              hipStream_t stream)
{
  (void)in_sizes; (void)n_in; (void)out_size; (void)ws_size;
  const float* pair  = (const float*)d_in[0];
  const float* sing  = (const float*)d_in[1];
  const float* bbr   = (const float*)d_in[2];
  const float* bbt   = (const float*)d_in[3];
  const float* Wqkv  = (const float*)d_in[4];
  const float* Wqk   = (const float*)d_in[5];
  const float* Wfc1  = (const float*)d_in[6];
  const float* bfc1  = (const float*)d_in[7];
  const float* W0    = (const float*)d_in[8];
  const float* W1    = (const float*)d_in[9];
  const float* gamma = (const float*)d_in[10];
  float* out = (float*)d_out;

  float* ws    = (float*)d_ws;
  float* rq    = ws;
  float* rk    = rq  + SZ_R;
  float* rv    = rk  + SZ_R;
  float* TqF   = rv  + SZ_R;
  float* TkF   = TqF + SZ_T;
  float* Qsq   = TkF + SZ_T;
  float* Ksq   = Qsq + SZ_S;
  float* attn  = Ksq + SZ_S;
  float* o_ihd = attn + SZ_A;
  float* top   = o_ihd + SZ_O;

  k_proj<<<dim3(Bb*Rr/K1_ROWS), dim3(256), 0, stream>>>(
      sing, Wqkv, Wqk, bbr, bbt, rq, rk, rv, TqF, TkF, Qsq, Ksq);
  k_pbias<<<dim3(Bb*Rr*Rr/64), dim3(256), 0, stream>>>(pair, Wfc1, bfc1, attn);
  k_scores<<<dim3(Bb*Hh*(Rr/ITILE)), dim3(256), 0, stream>>>(
      rq, rk, TqF, TkF, Qsq, Ksq, gamma, attn);
  k_agg<<<dim3(Bb*Rr), dim3(256), 0, stream>>>(attn, pair, rv, o_ihd, top);
  k_final<<<dim3(Bb*Rr/K5_BM, 384/K5_BN), dim3(256), 0, stream>>>(o_ihd, top, W0, W1, out);
}

// Round 3
// 279.531 us; speedup vs baseline: 1.6208x; 1.3401x over previous
//
#include <hip/hip_runtime.h>
#include <math.h>

#define Bb   2
#define Rr   384
#define CMd  384
#define CZ   128
#define Hh   12
#define DHd  32

#define WL           1.7320508075688772f   // sqrt(3)
#define WC           4.242640687119285f    // sqrt(18) = (2/(9*4))^-0.5
#define INV_SQRT_DH  0.17677669529663687f  // 32^-0.5

#define SZ_R   (Bb*Hh*Rr*DHd)      // 294912
#define SZ_T   (Bb*Hh*Rr*12)      // 110592
#define SZ_S   (Bb*Hh*Rr)         // 9216
#define SZ_A   ((long)Bb*Hh*Rr*Rr) // 3538944
#define SZ_O   (Bb*Rr*Hh*DHd)     // 294912

// ---------------------------------------------------------------- K1a: projection GEMM
// C[768,1440] = sing[768,384] @ [Wqkv | Wqk]; qkv cols scatter to rq/rk/rv,
// qk cols go to gbuf (row-major [768][288]) for k_frame.
#define G_BM 64
#define G_BN 64
#define G_BK 32
__global__ __launch_bounds__(256) void k_projgemm(
    const float* __restrict__ sing, const float* __restrict__ Wqkv,
    const float* __restrict__ Wqk,
    float* __restrict__ rq, float* __restrict__ rk, float* __restrict__ rv,
    float* __restrict__ gbuf)
{
  const int t = threadIdx.x;
  const int m0 = blockIdx.x * G_BM;
  const int n0 = blockIdx.y * G_BN;
  const int tx = t & 15, ty = t >> 4;
  __shared__ float As[G_BK][G_BM + 4];
  __shared__ float Bs[G_BK][G_BN + 4];
  float acc[4][4] = {};

  for (int kc = 0; kc < 384; kc += G_BK) {
    // stage A transposed: As[k][row]; 64 rows x 32 k = 512 float4 loads
    for (int l = t; l < 512; l += 256) {
      int row = l >> 3;
      int k4  = (l & 7) << 2;
      float4 v = *(const float4*)(sing + (long)(m0 + row)*384 + kc + k4);
      As[k4  ][row] = v.x; As[k4+1][row] = v.y;
      As[k4+2][row] = v.z; As[k4+3][row] = v.w;
    }
    // stage B: Bs[k][col]; 32 k x 64 n
    for (int l = t; l < 512; l += 256) {
      int k  = l >> 4;
      int c4 = (l & 15) << 2;
      int n  = n0 + c4;
      int gk = kc + k;
      float4 v;
      if (n < 1152)      v = *(const float4*)(Wqkv + (long)gk*1152 + n);
      else if (n < 1440) v = *(const float4*)(Wqk  + (long)gk*288 + (n - 1152));
      else               v = make_float4(0.f, 0.f, 0.f, 0.f);
      Bs[k][c4] = v.x; Bs[k][c4+1] = v.y; Bs[k][c4+2] = v.z; Bs[k][c4+3] = v.w;
    }
    __syncthreads();
    #pragma unroll
    for (int k = 0; k < G_BK; ++k) {
      float4 a = *(const float4*)&As[k][ty*4];
      float4 b = *(const float4*)&Bs[k][tx*4];
      acc[0][0] += a.x*b.x; acc[0][1] += a.x*b.y; acc[0][2] += a.x*b.z; acc[0][3] += a.x*b.w;
      acc[1][0] += a.y*b.x; acc[1][1] += a.y*b.y; acc[1][2] += a.y*b.z; acc[1][3] += a.y*b.w;
      acc[2][0] += a.z*b.x; acc[2][1] += a.z*b.y; acc[2][2] += a.z*b.z; acc[2][3] += a.z*b.w;
      acc[3][0] += a.w*b.x; acc[3][1] += a.w*b.y; acc[3][2] += a.w*b.z; acc[3][3] += a.w*b.w;
    }
    __syncthreads();
  }
  // epilogue: scatter
  #pragma unroll
  for (int j = 0; j < 4; ++j) {
    int n = n0 + tx*4 + j;
    if (n >= 1440) continue;
    if (n < 1152) {
      int d = n/36, rem = n - d*36, which = rem/12, h = rem - which*12;
      float* dst = (which == 0) ? rq : (which == 1) ? rk : rv;
      #pragma unroll
      for (int i = 0; i < 4; ++i) {
        int row = m0 + ty*4 + i, b = row / Rr, r = row - b*Rr;
        dst[(((long)b*Hh + h)*Rr + r)*DHd + d] = acc[i][j];
      }
    } else {
      int c2 = n - 1152;
      #pragma unroll
      for (int i = 0; i < 4; ++i)
        gbuf[(long)(m0 + ty*4 + i)*288 + c2] = acc[i][j];
    }
  }
}

// ---------------------------------------------------------------- K1b: frame transform
// one thread per (row, h, s2): T = g . bbr + bbt, plus |T|^2 sums
__global__ __launch_bounds__(256) void k_frame(
    const float* __restrict__ gbuf, const float* __restrict__ bbr,
    const float* __restrict__ bbt,
    float* __restrict__ TqF, float* __restrict__ TkF,
    float* __restrict__ Qsq, float* __restrict__ Ksq)
{
  const int idx = blockIdx.x*256 + threadIdx.x;   // 768*24 exact
  const int row = idx / 24, q = idx - row*24;
  const int h = q >> 1, s2 = q & 1;
  const float* gp = gbuf + (long)row*288 + h*24 + s2*12;
  float rot[9], tr[3];
  #pragma unroll
  for (int a = 0; a < 9; ++a) rot[a] = bbr[(long)row*9 + a];
  #pragma unroll
  for (int a = 0; a < 3; ++a) tr[a] = bbt[(long)row*3 + a];
  const int b = row / Rr, r = row - b*Rr;
  float* T = s2 ? TkF : TqF;
  const long tb = (((long)b*Hh + h)*Rr + r)*12;
  float v[12]; float ss = 0.f;
  #pragma unroll
  for (int p = 0; p < 4; ++p)
    #pragma unroll
    for (int k2 = 0; k2 < 3; ++k2) {
      float x = gp[p*3+0]*rot[k2] + gp[p*3+1]*rot[3+k2] + gp[p*3+2]*rot[6+k2] + tr[k2];
      v[p*3+k2] = x; ss += x*x;
    }
  *(float4*)(T + tb)     = make_float4(v[0], v[1], v[2],  v[3]);
  *(float4*)(T + tb + 4) = make_float4(v[4], v[5], v[6],  v[7]);
  *(float4*)(T + tb + 8) = make_float4(v[8], v[9], v[10], v[11]);
  (s2 ? Ksq : Qsq)[((long)b*Hh + h)*Rr + r] = ss;
}

// ---------------------------------------------------------------- K2: pair bias
__global__ __launch_bounds__(256) void k_pbias(
    const float* __restrict__ pair, const float* __restrict__ Wfc1,
    const float* __restrict__ bfc1, float* __restrict__ pb)
{
  const int t = threadIdx.x;
  const long base = (long)blockIdx.x * 64;   // 64 (b,i,j) rows per block
  __shared__ float tile[64][129];            // +1 pad: conflict-free
  __shared__ float w_l[128][12];
  __shared__ float bias_l[12];
  for (int idx = t; idx < 128*12; idx += 256) w_l[idx/12][idx%12] = Wfc1[idx];
  if (t < 12) bias_l[t] = bfc1[t];
  const float4* src = (const float4*)(pair + base*CZ);
  for (int idx = t; idx < 64*32; idx += 256) {
    float4 v = src[idx];
    int row = idx >> 5, c4 = (idx & 31) << 2;
    tile[row][c4] = v.x; tile[row][c4+1] = v.y; tile[row][c4+2] = v.z; tile[row][c4+3] = v.w;
  }
  __syncthreads();
  int row = t & 63;
  long n = base + row;
  int b = (int)(n / ((long)Rr*Rr));
  long rr2 = n - (long)b*Rr*Rr;
  int i = (int)(rr2 / Rr), j = (int)(rr2 - (long)i*Rr);
  int h0 = t >> 6;                           // h = h0, h0+4, h0+8
  float a0 = bias_l[h0], a1 = bias_l[h0+4], a2 = bias_l[h0+8];
  for (int c = 0; c < 128; ++c) {
    float v = tile[row][c];
    a0 += v*w_l[c][h0]; a1 += v*w_l[c][h0+4]; a2 += v*w_l[c][h0+8];
  }
  long o = (((long)b*Hh + h0)*Rr + i)*Rr + j;
  const long hstride = (long)Rr*Rr*4;
  pb[o] = a0; pb[o + hstride] = a1; pb[o + 2*hstride] = a2;
}

// ---------------------------------------------------------------- K3: scores + softmax
#define ITILE 8
__global__ __launch_bounds__(256) void k_scores(
    const float* __restrict__ rq, const float* __restrict__ rk,
    const float* __restrict__ TqF, const float* __restrict__ TkF,
    const float* __restrict__ Qsq, const float* __restrict__ Ksq,
    const float* __restrict__ gamma, float* __restrict__ attn)
{
  const int t = threadIdx.x;
  const int nt = Rr / ITILE;                 // 48
  const int bh = blockIdx.x / nt;
  const int i0 = (blockIdx.x - bh*nt) * ITILE;
  __shared__ float rk_l[384][33];            // 50.7 KB, conflict-free
  __shared__ float rq_l[32];
  __shared__ float tq_l[12];
  __shared__ float scal[1];
  __shared__ float redm[4], reds[4];

  for (int idx = t; idx < 384*32; idx += 256)
    rk_l[idx >> 5][idx & 31] = rk[(long)bh*Rr*DHd + idx];

  const float g0 = gamma[0];
  const float head_w = log1pf(__expf(g0)) * (WC * 0.5f);

  for (int ii = 0; ii < ITILE; ++ii) {
    const int i = i0 + ii;
    if (t < 32) rq_l[t] = rq[((long)bh*Rr + i)*DHd + t];
    if (t < 12) tq_l[t] = TqF[((long)bh*Rr + i)*12 + t];
    if (t == 0) scal[0] = Qsq[(long)bh*Rr + i];
    __syncthreads();                         // also covers rk_l staging (first iter)
    const float qs = scal[0];
    const long rowbase = ((long)bh*Rr + i)*Rr;

    auto logit_at = [&](int j) -> float {
      float dt = 0.f;
      #pragma unroll
      for (int dd = 0; dd < 32; ++dd) dt += rq_l[dd] * rk_l[j][dd];
      const float4* tk = (const float4*)(TkF + ((long)bh*Rr + j)*12);
      float4 ta = tk[0], tb = tk[1], tc = tk[2];
      float pt = tq_l[0]*ta.x + tq_l[1]*ta.y + tq_l[2]*ta.z + tq_l[3]*ta.w
               + tq_l[4]*tb.x + tq_l[5]*tb.y + tq_l[6]*tb.z + tq_l[7]*tb.w
               + tq_l[8]*tc.x + tq_l[9]*tc.y + tq_l[10]*tc.z + tq_l[11]*tc.w;
      float sqv = qs + Ksq[(long)bh*Rr + j] - 2.f*pt;
      return WL * (attn[rowbase + j] + dt*INV_SQRT_DH + head_w*sqv);
    };

    float l0 = logit_at(t);
    float l1 = (t < 128) ? logit_at(t + 256) : -3.4e38f;
    float m = fmaxf(l0, l1);
    #pragma unroll
    for (int s = 32; s; s >>= 1) m = fmaxf(m, __shfl_xor(m, s, 64));
    if ((t & 63) == 0) redm[t >> 6] = m;
    __syncthreads();
    m = fmaxf(fmaxf(redm[0], redm[1]), fmaxf(redm[2], redm[3]));
    float e0 = __expf(l0 - m);
    float e1 = (t < 128) ? __expf(l1 - m) : 0.f;
    float s = e0 + e1;
    #pragma unroll
    for (int sh = 32; sh; sh >>= 1) s += __shfl_xor(s, sh, 64);
    if ((t & 63) == 0) reds[t >> 6] = s;
    __syncthreads();
    float inv = 1.f / (reds[0] + reds[1] + reds[2] + reds[3]);
    attn[rowbase + t] = e0 * inv;
    if (t < 128) attn[rowbase + t + 256] = e1 * inv;
    __syncthreads();
  }
}

// ---------------------------------------------------------------- K4: value aggregation
__global__ __launch_bounds__(256) void k_agg(
    const float* __restrict__ attn, const float* __restrict__ pair,
    const float* __restrict__ rv, float* __restrict__ o_ihd, float* __restrict__ top)
{
  const int t = threadIdx.x;
  const int bi = blockIdx.x;                 // b*R + i
  const int b = bi / Rr;
  const int i = bi - b*Rr;
  __shared__ float a_l[12][384];
  for (int idx = t; idx < 12*384; idx += 256) {
    int h = idx / 384, j = idx - h*384;
    a_l[h][j] = attn[(((long)b*Hh + h)*Rr + i)*Rr + j];
  }
  __syncthreads();
  // Part A: top[b,i,h,c] = sum_j attn[h][j] * pair[b,i,j,c]
  const int c = t & 127, hh = t >> 7;        // hh in {0,1}; h = hh + 2m
  const float* prow = pair + (long)bi * Rr * CZ;
  float acc0=0,acc1=0,acc2=0,acc3=0,acc4=0,acc5=0;
  for (int j = 0; j < 384; ++j) {
    float v = prow[(long)j*CZ + c];
    acc0 += a_l[hh   ][j]*v;
    acc1 += a_l[hh+2 ][j]*v;
    acc2 += a_l[hh+4 ][j]*v;
    acc3 += a_l[hh+6 ][j]*v;
    acc4 += a_l[hh+8 ][j]*v;
    acc5 += a_l[hh+10][j]*v;
  }
  float* tp = top + ((long)bi*Hh)*CZ + c;
  tp[(long)(hh   )*CZ] = acc0;
  tp[(long)(hh+2 )*CZ] = acc1;
  tp[(long)(hh+4 )*CZ] = acc2;
  tp[(long)(hh+6 )*CZ] = acc3;
  tp[(long)(hh+8 )*CZ] = acc4;
  tp[(long)(hh+10)*CZ] = acc5;
  // Part B: o[b,i,h,d] = sum_j attn[h][j] * rv[b,h,j,d]
  for (int o = t; o < 384; o += 256) {
    int h = o >> 5, dd = o & 31;
    const float* rvp = rv + ((long)b*Hh + h)*Rr*DHd + dd;
    float s = 0.f;
    for (int j = 0; j < 384; ++j) s += a_l[h][j] * rvp[(long)j*DHd];
    o_ihd[(long)bi*384 + o] = s;
  }
}

// ---------------------------------------------------------------- K5: output GEMM
// out[768,384] = A[768,1920] @ W[1920,384], A = [o_ihd | top], W = [W0 ; W1]
#define K5_BM 8
#define K5_BN 64
#define K5_KC 128
__global__ __launch_bounds__(256) void k_final(
    const float* __restrict__ o_ihd, const float* __restrict__ top,
    const float* __restrict__ W0, const float* __restrict__ W1,
    float* __restrict__ out)
{
  const int t = threadIdx.x;
  const int row0 = blockIdx.x * K5_BM;       // 0..760
  const int col  = blockIdx.y * K5_BN + (t & 63);
  const int rg   = t >> 6;                   // 0..3 -> rows rg*2, rg*2+1
  __shared__ float Al[K5_BM][K5_KC + 4];

  float acc0 = 0.f, acc1 = 0.f;
  const int r0 = rg * 2, r1 = rg * 2 + 1;

  for (int kc = 0; kc < 1920; kc += K5_KC) {
    {
      int srow = t >> 5;
      int sc4  = (t & 31) << 2;
      int gk   = kc + sc4;
      const float* src;
      if (gk < 384) src = o_ihd + (long)(row0 + srow)*384 + gk;
      else          src = top   + (long)(row0 + srow)*1536 + (gk - 384);
      float4 v = *(const float4*)src;
      Al[srow][sc4] = v.x; Al[srow][sc4+1] = v.y; Al[srow][sc4+2] = v.z; Al[srow][sc4+3] = v.w;
    }
    __syncthreads();
    const float* wbase;
    if (kc < 384) wbase = W0 + (long)kc*384 + col;
    else          wbase = W1 + (long)(kc - 384)*384 + col;
    #pragma unroll 8
    for (int k = 0; k < K5_KC; ++k) {
      float w = wbase[(long)k * 384];
      acc0 += Al[r0][k] * w;
      acc1 += Al[r1][k] * w;
    }
    __syncthreads();
  }
  out[(long)(row0 + r0)*384 + col] = acc0;
  out[(long)(row0 + r1)*384 + col] = acc1;
}

// ---------------------------------------------------------------- launch
extern "C" void kernel_launch(void* const* d_in, const int* in_sizes, int n_in,
                              void* d_out, int out_size, void* d_ws, size_t ws_size,
                              hipStream_t stream)
{
  (void)in_sizes; (void)n_in; (void)out_size; (void)ws_size;
  const float* pair  = (const float*)d_in[0];
  const float* sing  = (const float*)d_in[1];
  const float* bbr   = (const float*)d_in[2];
  const float* bbt   = (const float*)d_in[3];
  const float* Wqkv  = (const float*)d_in[4];
  const float* Wqk   = (const float*)d_in[5];
  const float* Wfc1  = (const float*)d_in[6];
  const float* bfc1  = (const float*)d_in[7];
  const float* W0    = (const float*)d_in[8];
  const float* W1    = (const float*)d_in[9];
  const float* gamma = (const float*)d_in[10];
  float* out = (float*)d_out;

  float* ws    = (float*)d_ws;
  float* rq    = ws;
  float* rk    = rq  + SZ_R;
  float* rv    = rk  + SZ_R;
  float* TqF   = rv  + SZ_R;
  float* TkF   = TqF + SZ_T;
  float* Qsq   = TkF + SZ_T;
  float* Ksq   = Qsq + SZ_S;
  float* attn  = Ksq + SZ_S;
  float* o_ihd = attn + SZ_A;
  float* top   = o_ihd + SZ_O;
  float* gbuf  = o_ihd;   // alias: gbuf (768*288) consumed by k_frame before k_agg writes o_ihd

  k_projgemm<<<dim3(Bb*Rr/G_BM, (1440 + G_BN - 1)/G_BN), dim3(256), 0, stream>>>(
      sing, Wqkv, Wqk, rq, rk, rv, gbuf);
  k_frame<<<dim3(Bb*Rr*24/256), dim3(256), 0, stream>>>(
      gbuf, bbr, bbt, TqF, TkF, Qsq, Ksq);
  k_pbias<<<dim3(Bb*Rr*Rr/64), dim3(256), 0, stream>>>(pair, Wfc1, bfc1, attn);
  k_scores<<<dim3(Bb*Hh*(Rr/ITILE)), dim3(256), 0, stream>>>(
      rq, rk, TqF, TkF, Qsq, Ksq, gamma, attn);
  k_agg<<<dim3(Bb*Rr), dim3(256), 0, stream>>>(attn, pair, rv, o_ihd, top);
  k_final<<<dim3(Bb*Rr/K5_BM, 384/K5_BN), dim3(256), 0, stream>>>(o_ihd, top, W0, W1, out);
}

// Round 4
// 230.488 us; speedup vs baseline: 1.9656x; 1.2128x over previous
//
#include <hip/hip_runtime.h>
#include <math.h>

#define Bb   2
#define Rr   384
#define CMd  384
#define CZ   128
#define Hh   12
#define DHd  32

#define WL           1.7320508075688772f   // sqrt(3)
#define WC           4.242640687119285f    // sqrt(18) = (2/(9*4))^-0.5
#define INV_SQRT_DH  0.17677669529663687f  // 32^-0.5

#define SZ_R   (Bb*Hh*Rr*DHd)      // 294912
#define SZ_T   (Bb*Hh*Rr*12)      // 110592
#define SZ_S   (Bb*Hh*Rr)         // 9216
#define SZ_A   ((long)Bb*Hh*Rr*Rr) // 3538944
#define SZ_O   (Bb*Rr*Hh*DHd)     // 294912

// ---------------------------------------------------------------- K1a: projection GEMM
// C[768,1440] = sing[768,384] @ [Wqkv | Wqk]; qkv cols scatter to rq/rk/rv,
// qk cols go to gbuf (row-major [768][288]) for k_frame.
#define G_BM 64
#define G_BN 64
#define G_BK 32
__global__ __launch_bounds__(256) void k_projgemm(
    const float* __restrict__ sing, const float* __restrict__ Wqkv,
    const float* __restrict__ Wqk,
    float* __restrict__ rq, float* __restrict__ rk, float* __restrict__ rv,
    float* __restrict__ gbuf)
{
  const int t = threadIdx.x;
  const int m0 = blockIdx.x * G_BM;
  const int n0 = blockIdx.y * G_BN;
  const int tx = t & 15, ty = t >> 4;
  __shared__ float As[G_BK][G_BM + 4];
  __shared__ float Bs[G_BK][G_BN + 4];
  float acc[4][4] = {};

  for (int kc = 0; kc < 384; kc += G_BK) {
    for (int l = t; l < 512; l += 256) {
      int row = l >> 3;
      int k4  = (l & 7) << 2;
      float4 v = *(const float4*)(sing + (long)(m0 + row)*384 + kc + k4);
      As[k4  ][row] = v.x; As[k4+1][row] = v.y;
      As[k4+2][row] = v.z; As[k4+3][row] = v.w;
    }
    for (int l = t; l < 512; l += 256) {
      int k  = l >> 4;
      int c4 = (l & 15) << 2;
      int n  = n0 + c4;
      int gk = kc + k;
      float4 v;
      if (n < 1152)      v = *(const float4*)(Wqkv + (long)gk*1152 + n);
      else if (n < 1440) v = *(const float4*)(Wqk  + (long)gk*288 + (n - 1152));
      else               v = make_float4(0.f, 0.f, 0.f, 0.f);
      Bs[k][c4] = v.x; Bs[k][c4+1] = v.y; Bs[k][c4+2] = v.z; Bs[k][c4+3] = v.w;
    }
    __syncthreads();
    #pragma unroll
    for (int k = 0; k < G_BK; ++k) {
      float4 a = *(const float4*)&As[k][ty*4];
      float4 b = *(const float4*)&Bs[k][tx*4];
      acc[0][0] += a.x*b.x; acc[0][1] += a.x*b.y; acc[0][2] += a.x*b.z; acc[0][3] += a.x*b.w;
      acc[1][0] += a.y*b.x; acc[1][1] += a.y*b.y; acc[1][2] += a.y*b.z; acc[1][3] += a.y*b.w;
      acc[2][0] += a.z*b.x; acc[2][1] += a.z*b.y; acc[2][2] += a.z*b.z; acc[2][3] += a.z*b.w;
      acc[3][0] += a.w*b.x; acc[3][1] += a.w*b.y; acc[3][2] += a.w*b.z; acc[3][3] += a.w*b.w;
    }
    __syncthreads();
  }
  #pragma unroll
  for (int j = 0; j < 4; ++j) {
    int n = n0 + tx*4 + j;
    if (n >= 1440) continue;
    if (n < 1152) {
      int d = n/36, rem = n - d*36, which = rem/12, h = rem - which*12;
      float* dst = (which == 0) ? rq : (which == 1) ? rk : rv;
      #pragma unroll
      for (int i = 0; i < 4; ++i) {
        int row = m0 + ty*4 + i, b = row / Rr, r = row - b*Rr;
        dst[(((long)b*Hh + h)*Rr + r)*DHd + d] = acc[i][j];
      }
    } else {
      int c2 = n - 1152;
      #pragma unroll
      for (int i = 0; i < 4; ++i)
        gbuf[(long)(m0 + ty*4 + i)*288 + c2] = acc[i][j];
    }
  }
}

// ---------------------------------------------------------------- K1b: frame transform
__global__ __launch_bounds__(256) void k_frame(
    const float* __restrict__ gbuf, const float* __restrict__ bbr,
    const float* __restrict__ bbt,
    float* __restrict__ TqF, float* __restrict__ TkF,
    float* __restrict__ Qsq, float* __restrict__ Ksq)
{
  const int idx = blockIdx.x*256 + threadIdx.x;   // 768*24 exact
  const int row = idx / 24, q = idx - row*24;
  const int h = q >> 1, s2 = q & 1;
  const float* gp = gbuf + (long)row*288 + h*24 + s2*12;
  float rot[9], tr[3];
  #pragma unroll
  for (int a = 0; a < 9; ++a) rot[a] = bbr[(long)row*9 + a];
  #pragma unroll
  for (int a = 0; a < 3; ++a) tr[a] = bbt[(long)row*3 + a];
  const int b = row / Rr, r = row - b*Rr;
  float* T = s2 ? TkF : TqF;
  const long tb = (((long)b*Hh + h)*Rr + r)*12;
  float v[12]; float ss = 0.f;
  #pragma unroll
  for (int p = 0; p < 4; ++p)
    #pragma unroll
    for (int k2 = 0; k2 < 3; ++k2) {
      float x = gp[p*3+0]*rot[k2] + gp[p*3+1]*rot[3+k2] + gp[p*3+2]*rot[6+k2] + tr[k2];
      v[p*3+k2] = x; ss += x*x;
    }
  *(float4*)(T + tb)     = make_float4(v[0], v[1], v[2],  v[3]);
  *(float4*)(T + tb + 4) = make_float4(v[4], v[5], v[6],  v[7]);
  *(float4*)(T + tb + 8) = make_float4(v[8], v[9], v[10], v[11]);
  (s2 ? Ksq : Qsq)[((long)b*Hh + h)*Rr + r] = ss;
}

// ---------------------------------------------------------------- K2: pair bias
__global__ __launch_bounds__(256) void k_pbias(
    const float* __restrict__ pair, const float* __restrict__ Wfc1,
    const float* __restrict__ bfc1, float* __restrict__ pb)
{
  const int t = threadIdx.x;
  const long base = (long)blockIdx.x * 64;   // 64 (b,i,j) rows per block
  __shared__ float tile[64][129];            // +1 pad: conflict-free
  __shared__ float w_l[128][12];
  __shared__ float bias_l[12];
  for (int idx = t; idx < 128*12; idx += 256) w_l[idx/12][idx%12] = Wfc1[idx];
  if (t < 12) bias_l[t] = bfc1[t];
  const float4* src = (const float4*)(pair + base*CZ);
  for (int idx = t; idx < 64*32; idx += 256) {
    float4 v = src[idx];
    int row = idx >> 5, c4 = (idx & 31) << 2;
    tile[row][c4] = v.x; tile[row][c4+1] = v.y; tile[row][c4+2] = v.z; tile[row][c4+3] = v.w;
  }
  __syncthreads();
  int row = t & 63;
  long n = base + row;
  int b = (int)(n / ((long)Rr*Rr));
  long rr2 = n - (long)b*Rr*Rr;
  int i = (int)(rr2 / Rr), j = (int)(rr2 - (long)i*Rr);
  int h0 = t >> 6;                           // h = h0, h0+4, h0+8
  float a0 = bias_l[h0], a1 = bias_l[h0+4], a2 = bias_l[h0+8];
  for (int c = 0; c < 128; ++c) {
    float v = tile[row][c];
    a0 += v*w_l[c][h0]; a1 += v*w_l[c][h0+4]; a2 += v*w_l[c][h0+8];
  }
  long o = (((long)b*Hh + h0)*Rr + i)*Rr + j;
  const long hstride = (long)Rr*Rr*4;
  pb[o] = a0; pb[o + hstride] = a1; pb[o + 2*hstride] = a2;
}

// ---------------------------------------------------------------- K3: scores + softmax
#define ITILE 8
__global__ __launch_bounds__(256) void k_scores(
    const float* __restrict__ rq, const float* __restrict__ rk,
    const float* __restrict__ TqF, const float* __restrict__ TkF,
    const float* __restrict__ Qsq, const float* __restrict__ Ksq,
    const float* __restrict__ gamma, float* __restrict__ attn)
{
  const int t = threadIdx.x;
  const int nt = Rr / ITILE;                 // 48
  const int bh = blockIdx.x / nt;
  const int i0 = (blockIdx.x - bh*nt) * ITILE;
  __shared__ float rk_l[384][33];            // 50.7 KB, conflict-free
  __shared__ float rq_l[32];
  __shared__ float tq_l[12];
  __shared__ float scal[1];
  __shared__ float redm[4], reds[4];

  for (int idx = t; idx < 384*32; idx += 256)
    rk_l[idx >> 5][idx & 31] = rk[(long)bh*Rr*DHd + idx];

  const float g0 = gamma[0];
  const float head_w = log1pf(__expf(g0)) * (WC * 0.5f);

  for (int ii = 0; ii < ITILE; ++ii) {
    const int i = i0 + ii;
    if (t < 32) rq_l[t] = rq[((long)bh*Rr + i)*DHd + t];
    if (t < 12) tq_l[t] = TqF[((long)bh*Rr + i)*12 + t];
    if (t == 0) scal[0] = Qsq[(long)bh*Rr + i];
    __syncthreads();
    const float qs = scal[0];
    const long rowbase = ((long)bh*Rr + i)*Rr;

    auto logit_at = [&](int j) -> float {
      float dt = 0.f;
      #pragma unroll
      for (int dd = 0; dd < 32; ++dd) dt += rq_l[dd] * rk_l[j][dd];
      const float4* tk = (const float4*)(TkF + ((long)bh*Rr + j)*12);
      float4 ta = tk[0], tb = tk[1], tc = tk[2];
      float pt = tq_l[0]*ta.x + tq_l[1]*ta.y + tq_l[2]*ta.z + tq_l[3]*ta.w
               + tq_l[4]*tb.x + tq_l[5]*tb.y + tq_l[6]*tb.z + tq_l[7]*tb.w
               + tq_l[8]*tc.x + tq_l[9]*tc.y + tq_l[10]*tc.z + tq_l[11]*tc.w;
      float sqv = qs + Ksq[(long)bh*Rr + j] - 2.f*pt;
      return WL * (attn[rowbase + j] + dt*INV_SQRT_DH + head_w*sqv);
    };

    float l0 = logit_at(t);
    float l1 = (t < 128) ? logit_at(t + 256) : -3.4e38f;
    float m = fmaxf(l0, l1);
    #pragma unroll
    for (int s = 32; s; s >>= 1) m = fmaxf(m, __shfl_xor(m, s, 64));
    if ((t & 63) == 0) redm[t >> 6] = m;
    __syncthreads();
    m = fmaxf(fmaxf(redm[0], redm[1]), fmaxf(redm[2], redm[3]));
    float e0 = __expf(l0 - m);
    float e1 = (t < 128) ? __expf(l1 - m) : 0.f;
    float s = e0 + e1;
    #pragma unroll
    for (int sh = 32; sh; sh >>= 1) s += __shfl_xor(s, sh, 64);
    if ((t & 63) == 0) reds[t >> 6] = s;
    __syncthreads();
    float inv = 1.f / (reds[0] + reds[1] + reds[2] + reds[3]);
    attn[rowbase + t] = e0 * inv;
    if (t < 128) attn[rowbase + t + 256] = e1 * inv;
    __syncthreads();
  }
}

// ---------------------------------------------------------------- K4: value aggregation
__global__ __launch_bounds__(256) void k_agg(
    const float* __restrict__ attn, const float* __restrict__ pair,
    const float* __restrict__ rv, float* __restrict__ o_ihd, float* __restrict__ top)
{
  const int t = threadIdx.x;
  const int bi = blockIdx.x;                 // b*R + i
  const int b = bi / Rr;
  const int i = bi - b*Rr;
  __shared__ float a_l[12][384];
  for (int idx = t; idx < 12*384; idx += 256) {
    int h = idx / 384, j = idx - h*384;
    a_l[h][j] = attn[(((long)b*Hh + h)*Rr + i)*Rr + j];
  }
  __syncthreads();
  const int c = t & 127, hh = t >> 7;
  const float* prow = pair + (long)bi * Rr * CZ;
  float acc0=0,acc1=0,acc2=0,acc3=0,acc4=0,acc5=0;
  for (int j = 0; j < 384; ++j) {
    float v = prow[(long)j*CZ + c];
    acc0 += a_l[hh   ][j]*v;
    acc1 += a_l[hh+2 ][j]*v;
    acc2 += a_l[hh+4 ][j]*v;
    acc3 += a_l[hh+6 ][j]*v;
    acc4 += a_l[hh+8 ][j]*v;
    acc5 += a_l[hh+10][j]*v;
  }
  float* tp = top + ((long)bi*Hh)*CZ + c;
  tp[(long)(hh   )*CZ] = acc0;
  tp[(long)(hh+2 )*CZ] = acc1;
  tp[(long)(hh+4 )*CZ] = acc2;
  tp[(long)(hh+6 )*CZ] = acc3;
  tp[(long)(hh+8 )*CZ] = acc4;
  tp[(long)(hh+10)*CZ] = acc5;
  for (int o = t; o < 384; o += 256) {
    int h = o >> 5, dd = o & 31;
    const float* rvp = rv + ((long)b*Hh + h)*Rr*DHd + dd;
    float s = 0.f;
    for (int j = 0; j < 384; ++j) s += a_l[h][j] * rvp[(long)j*DHd];
    o_ihd[(long)bi*384 + o] = s;
  }
}

// ---------------------------------------------------------------- K5: output GEMM, split-K
// out[768,384] = A[768,1920] @ W[1920,384], A = [o_ihd | top], W = [W0 ; W1]
// BM=64, BN=64, BK=32, 4x4 microtile, KSPLIT chunks of 480 -> partials
#define K5_KSPLIT 4
#define K5_KLEN   480
__global__ __launch_bounds__(256) void k_final_part(
    const float* __restrict__ o_ihd, const float* __restrict__ top,
    const float* __restrict__ W0, const float* __restrict__ W1,
    float* __restrict__ partial)
{
  const int t = threadIdx.x;
  const int m0 = blockIdx.x * 64;
  const int n0 = blockIdx.y * 64;
  const int ks = blockIdx.z;
  const int tx = t & 15, ty = t >> 4;
  __shared__ float As[32][68];
  __shared__ float Bs[32][68];
  float acc[4][4] = {};

  const int kbeg = ks * K5_KLEN;
  for (int kc = kbeg; kc < kbeg + K5_KLEN; kc += 32) {
    for (int l = t; l < 512; l += 256) {
      int row = l >> 3;
      int k4  = (l & 7) << 2;
      int gk  = kc + k4;
      const float* src;
      if (gk < 384) src = o_ihd + (long)(m0 + row)*384 + gk;
      else          src = top   + (long)(m0 + row)*1536 + (gk - 384);
      float4 v = *(const float4*)src;
      As[k4  ][row] = v.x; As[k4+1][row] = v.y;
      As[k4+2][row] = v.z; As[k4+3][row] = v.w;
    }
    for (int l = t; l < 512; l += 256) {
      int k  = l >> 4;
      int c4 = (l & 15) << 2;
      int gk = kc + k;
      const float* src;
      if (gk < 384) src = W0 + (long)gk*384 + n0 + c4;
      else          src = W1 + (long)(gk - 384)*384 + n0 + c4;
      float4 v = *(const float4*)src;
      Bs[k][c4] = v.x; Bs[k][c4+1] = v.y; Bs[k][c4+2] = v.z; Bs[k][c4+3] = v.w;
    }
    __syncthreads();
    #pragma unroll
    for (int k = 0; k < 32; ++k) {
      float4 a = *(const float4*)&As[k][ty*4];
      float4 b = *(const float4*)&Bs[k][tx*4];
      acc[0][0] += a.x*b.x; acc[0][1] += a.x*b.y; acc[0][2] += a.x*b.z; acc[0][3] += a.x*b.w;
      acc[1][0] += a.y*b.x; acc[1][1] += a.y*b.y; acc[1][2] += a.y*b.z; acc[1][3] += a.y*b.w;
      acc[2][0] += a.z*b.x; acc[2][1] += a.z*b.y; acc[2][2] += a.z*b.z; acc[2][3] += a.z*b.w;
      acc[3][0] += a.w*b.x; acc[3][1] += a.w*b.y; acc[3][2] += a.w*b.z; acc[3][3] += a.w*b.w;
    }
    __syncthreads();
  }
  float* pdst = partial + (long)ks * (768*384);
  #pragma unroll
  for (int i = 0; i < 4; ++i) {
    int row = m0 + ty*4 + i;
    #pragma unroll
    for (int j = 0; j < 4; ++j)
      pdst[(long)row*384 + n0 + tx*4 + j] = acc[i][j];
  }
}

__global__ __launch_bounds__(256) void k_final_reduce(
    const float* __restrict__ partial, float* __restrict__ out)
{
  const int idx = blockIdx.x*256 + threadIdx.x;   // over 73728 float4
  const float4* p0 = (const float4*)partial;
  const float4* p1 = (const float4*)(partial + 768*384);
  const float4* p2 = (const float4*)(partial + 2*768*384);
  const float4* p3 = (const float4*)(partial + 3*768*384);
  float4 a = p0[idx], b = p1[idx], c = p2[idx], d = p3[idx];
  float4 r;
  r.x = a.x + b.x + c.x + d.x;
  r.y = a.y + b.y + c.y + d.y;
  r.z = a.z + b.z + c.z + d.z;
  r.w = a.w + b.w + c.w + d.w;
  ((float4*)out)[idx] = r;
}

// ---------------------------------------------------------------- launch
extern "C" void kernel_launch(void* const* d_in, const int* in_sizes, int n_in,
                              void* d_out, int out_size, void* d_ws, size_t ws_size,
                              hipStream_t stream)
{
  (void)in_sizes; (void)n_in; (void)out_size; (void)ws_size;
  const float* pair  = (const float*)d_in[0];
  const float* sing  = (const float*)d_in[1];
  const float* bbr   = (const float*)d_in[2];
  const float* bbt   = (const float*)d_in[3];
  const float* Wqkv  = (const float*)d_in[4];
  const float* Wqk   = (const float*)d_in[5];
  const float* Wfc1  = (const float*)d_in[6];
  const float* bfc1  = (const float*)d_in[7];
  const float* W0    = (const float*)d_in[8];
  const float* W1    = (const float*)d_in[9];
  const float* gamma = (const float*)d_in[10];
  float* out = (float*)d_out;

  float* ws    = (float*)d_ws;
  float* rq    = ws;
  float* rk    = rq  + SZ_R;
  float* rv    = rk  + SZ_R;
  float* TqF   = rv  + SZ_R;
  float* TkF   = TqF + SZ_T;
  float* Qsq   = TkF + SZ_T;
  float* Ksq   = Qsq + SZ_S;
  float* attn  = Ksq + SZ_S;
  float* o_ihd = attn + SZ_A;
  float* top   = o_ihd + SZ_O;
  float* gbuf  = o_ihd;     // alias: consumed by k_frame before k_agg writes o_ihd
  float* partial = attn;    // alias: attn dead after k_agg; 4*294912 << SZ_A

  k_projgemm<<<dim3(Bb*Rr/G_BM, (1440 + G_BN - 1)/G_BN), dim3(256), 0, stream>>>(
      sing, Wqkv, Wqk, rq, rk, rv, gbuf);
  k_frame<<<dim3(Bb*Rr*24/256), dim3(256), 0, stream>>>(
      gbuf, bbr, bbt, TqF, TkF, Qsq, Ksq);
  k_pbias<<<dim3(Bb*Rr*Rr/64), dim3(256), 0, stream>>>(pair, Wfc1, bfc1, attn);
  k_scores<<<dim3(Bb*Hh*(Rr/ITILE)), dim3(256), 0, stream>>>(
      rq, rk, TqF, TkF, Qsq, Ksq, gamma, attn);
  k_agg<<<dim3(Bb*Rr), dim3(256), 0, stream>>>(attn, pair, rv, o_ihd, top);
  k_final_part<<<dim3(Bb*Rr/64, 384/64, K5_KSPLIT), dim3(256), 0, stream>>>(
      o_ihd, top, W0, W1, partial);
  k_final_reduce<<<dim3(768*384/4/256), dim3(256), 0, stream>>>(partial, out);
}